// Round 3
// baseline (1479.305 us; speedup 1.0000x reference)
//
#include <hip/hip_runtime.h>

// PositionalEncoding — ALL tensors are float32 on device.
// Forensics: R1 (pe read as bf16-ushort) gave error exactly 2^65 (bf16 decode
// of f32 mantissa fragments); R2 (all read as bf16) gave 8.27 (= misplaced
// source rows from half-stride reads of f32 buffers). The harness upcasts the
// reference's f16 pe to f32; output dtype = mem.dtype = f32.
// Shapes:
//   mem        (256, 30, 128)  f32
//   can        (256, 200, 128) f32
//   mem_bboxes (256, 30, 4)    f32
//   can_bboxes (256, 99, 4)    f32
//   pe         (211, 211, 61, 128) f32
//   out        (256, 230, 128) f32
constexpr int Bsz     = 256;
constexpr int MEM_LEN = 30;
constexpr int CAN_LEN = 200;
constexpr int NC      = 99;
constexpr int D       = 128;
constexpr int L_TOT   = MEM_LEN + CAN_LEN;   // 230
constexpr int PE_Y    = 211;
constexpr int PE_Z    = 61;

__global__ __launch_bounds__(256) void pe_add_kernel(
    const float* __restrict__ mem,
    const float* __restrict__ can,
    const float* __restrict__ mem_bb,
    const float* __restrict__ can_bb,
    const float* __restrict__ pe,
    float*       __restrict__ out)
{
    int g   = blockIdx.x * blockDim.x + threadIdx.x;
    int row = g >> 5;                    // 32 lanes per row (128 f32 / float4)
    if (row >= Bsz * L_TOT) return;
    int d   = (g & 31) * 4;
    int b   = row / L_TOT;
    int l   = row - b * L_TOT;

    // reference bbox = mem_bboxes[b, 29, :]
    const float4 rb = *(const float4*)(mem_bb + (b * MEM_LEN + (MEM_LEN - 1)) * 4);
    float w_r  = rb.z - rb.x + 1.0f;
    float h_r  = rb.w - rb.y + 1.0f;
    float cx_r = (rb.x + rb.z) * 0.5f;
    float cy_r = (rb.y + rb.w) * 0.5f;

    float4 bb;
    int t_idx;
    const float* src;
    if (l < MEM_LEN) {
        bb = *(const float4*)(mem_bb + (b * MEM_LEN + l) * 4);
        // mem_t: v = l-29 in [-29..0]; idx = clip(2v, -30, 30) + 30
        int tv = 2 * (l - (MEM_LEN - 1));
        t_idx  = (tv < -30 ? -30 : tv) + 30;
        src    = mem + (size_t)(b * MEM_LEN + l) * D;
    } else {
        int j = l - MEM_LEN;             // 0..199
        // can_bb: odd j < 198 -> can_bboxes[(j-1)/2]; else ref bbox
        if ((j & 1) && j < 2 * NC) {
            bb = *(const float4*)(can_bb + (b * NC + (j >> 1)) * 4);
        } else {
            bb = rb;
        }
        // can_t: v = 1 (even j) or 2 (odd j); idx = 2v + 30
        t_idx = (j & 1) ? 34 : 32;
        src   = can + (size_t)(b * CAN_LEN + j) * D;
    }

    // _distance_values in f32, mirroring numpy op-for-op:
    // each mul/add/div individually rounded; block fma contraction on the sum.
    float w  = bb.z - bb.x + 1.0f;
    float h  = bb.w - bb.y + 1.0f;
    float cx = (bb.x + bb.z) * 0.5f;
    float cy = (bb.y + bb.w) * 0.5f;
    float dx = (cx - cx_r) / w_r;
    float dy = (cy - cy_r) / h_r;
    float ss = __fadd_rn(__fmul_rn(dx, dx), __fmul_rn(dy, dy));
    float xy = __fsqrt_rn(ss);                    // correctly rounded, = np.sqrt
    float sz = 0.5f * logf(__fmul_rn(w, h) / __fmul_rn(w_r, h_r));

    // _clip_idx: clip(v*15, -105, 105) -> trunc toward zero -> +105
    float xv = fminf(fmaxf(xy * 15.0f, -105.0f), 105.0f);
    float yv = fminf(fmaxf(sz * 15.0f, -105.0f), 105.0f);
    int xi = (int)xv + 105;
    int yi = (int)yv + 105;

    const float* pr = pe + ((size_t)((xi * PE_Y + yi) * PE_Z + t_idx)) * D + d;
    float4 pv = *(const float4*)pr;               // 16 B, aligned (d mult of 4)
    float4 iv = *(const float4*)(src + d);

    float4 ov;
    ov.x = iv.x + pv.x;
    ov.y = iv.y + pv.y;
    ov.z = iv.z + pv.z;
    ov.w = iv.w + pv.w;
    *(float4*)(out + (size_t)row * D + d) = ov;
}

extern "C" void kernel_launch(void* const* d_in, const int* in_sizes, int n_in,
                              void* d_out, int out_size, void* d_ws, size_t ws_size,
                              hipStream_t stream) {
    const float* mem    = (const float*)d_in[0];
    const float* can    = (const float*)d_in[1];
    const float* mem_bb = (const float*)d_in[2];
    const float* can_bb = (const float*)d_in[3];
    const float* pe     = (const float*)d_in[4];
    float*       out    = (float*)d_out;

    const int total = Bsz * L_TOT * (D / 4);   // 1,884,160 threads
    const int block = 256;
    const int grid  = (total + block - 1) / block;  // 7360
    pe_add_kernel<<<grid, block, 0, stream>>>(mem, can, mem_bb, can_bb, pe, out);
}